// Round 3
// baseline (450.331 us; speedup 1.0000x reference)
//
#include <hip/hip_runtime.h>
#include <hip/hip_bf16.h>
#include <math.h>

// Problem constants (match reference)
#define IN_C 31
#define OUT_C 31
#define GRIDSZ 5
#define KORD 3
#define NUM_BASIS 8            // GRIDSZ + KORD
#define UW_OFF 7688            // COEF_LEN
#define RW_OFF 8649            // COEF_LEN + UW_LEN
#define NPIX 16384             // 128*128

// Layout: one pixel per LANE. Block = 256 threads = 4 waves, all covering the
// same 64 pixels; wave w owns output channels {o0, o0+1} with
// o0 = (blockIdx.y*4 + w)*2. Grid = (256 pixel-groups, 4 o-groups) = 1024
// blocks -> 4096 waves = 4 waves/SIMD.
//
// Weight addresses are wave-uniform -> scalar s_load; each 64B scalar fetch
// feeds 16 wave-wide v_fmac_f32. NO runtime-indexed arrays (xl[] only ever
// statically indexed inside fully-unrolled c-loops; the per-i value is
// re-loaded from L1) -> zero scratch, unlike round 2's 57 MB spill traffic.

__global__ __launch_bounds__(256) void kan_fused3_kernel(
    const float* __restrict__ x,     // (31, 16384)
    const float* __restrict__ gw,    // (9610, 31)
    const float* __restrict__ gb,    // (9610,)
    float* __restrict__ out)         // (31, 16384)
{
    const int lane = threadIdx.x & 63;
    const int w    = __builtin_amdgcn_readfirstlane(threadIdx.x >> 6); // 0..3
    const int pix  = blockIdx.x * 64 + lane;
    const int o0   = (blockIdx.y * 4 + w) * 2;            // 0,2,...,30
    const int nO   = (o0 + 2 <= OUT_C) ? 2 : 1;           // o0==30 -> 1

    // Pixel's 31 channels in registers (coalesced: lane = consecutive pixel).
    float xl[IN_C];
#pragma unroll
    for (int c = 0; c < IN_C; ++c)
        xl[c] = x[c * NPIX + pix];

    float y0 = 0.f, y1 = 0.f;

    const float h = 2.0f / (float)GRIDSZ;

#pragma unroll 1
    for (int i = 0; i < IN_C; ++i) {
        // Re-load instead of xl[i]: dynamic array indexing would demote xl to
        // scratch. This is an L1 hit (same line as the round-0 load).
        const float xv = x[i * NPIX + pix];

        // ---- Cox-de Boor basis (exact replication of reference recursion) ----
        float g[GRIDSZ + 2 * KORD + 1];  // 12 knots, compile-time constants
#pragma unroll
        for (int j = 0; j < GRIDSZ + 2 * KORD + 1; ++j)
            g[j] = (float)(j - KORD) * h - 1.0f;

        float b[GRIDSZ + 2 * KORD];      // 11 -> 10 -> 9 -> 8
#pragma unroll
        for (int j = 0; j < GRIDSZ + 2 * KORD; ++j)
            b[j] = (xv >= g[j] && xv < g[j + 1]) ? 1.0f : 0.0f;

#pragma unroll
        for (int pd = 1; pd <= KORD; ++pd) {
#pragma unroll
            for (int j = 0; j < GRIDSZ + 2 * KORD - pd; ++j) {
                const float left  = (xv - g[j]) * (1.0f / (g[j + pd] - g[j])) * b[j];
                const float right = (g[j + pd + 1] - xv) * (1.0f / (g[j + pd + 1] - g[j + 1])) * b[j + 1];
                b[j] = left + right;
            }
        }

        // silu(x) = x / (1 + exp(-x))
        const float sil = xv / (1.0f + __expf(-xv));

#pragma unroll
        for (int jo = 0; jo < 2; ++jo) {
            if (jo < nO) {                       // wave-uniform guard
                const int o  = o0 + jo;
                const int po = i * OUT_C + o;

                // ---- spline = sum_k basis_k * (gw_coef[po,k,:] . x + gb) ----
                const float* wc = gw + (size_t)po * (NUM_BASIS * IN_C);
                const float* cb = gb + po * NUM_BASIS;
                float sp0 = 0.f, sp1 = 0.f;
#pragma unroll
                for (int k = 0; k < NUM_BASIS; ++k) {
                    // two independent accumulator chains for ILP
                    float cka = cb[k];
                    float ckb = 0.f;
#pragma unroll
                    for (int c = 0; c + 1 < IN_C; c += 2) {
                        cka = fmaf(wc[k * IN_C + c],     xl[c],     cka);
                        ckb = fmaf(wc[k * IN_C + c + 1], xl[c + 1], ckb);
                    }
                    cka = fmaf(wc[k * IN_C + (IN_C - 1)], xl[IN_C - 1], cka);
                    const float ck = cka + ckb;
                    if (k & 1) sp1 = fmaf(b[k], ck, sp1);
                    else       sp0 = fmaf(b[k], ck, sp0);
                }
                const float spline = sp0 + sp1;

                // ---- uw, rw dots ----
                const float* wu = gw + (size_t)(UW_OFF + po) * IN_C;
                const float* wr = gw + (size_t)(RW_OFF + po) * IN_C;
                float uwv = gb[UW_OFF + po];
                float rwv = gb[RW_OFF + po];
#pragma unroll
                for (int c = 0; c < IN_C; ++c) {
                    uwv = fmaf(wu[c], xl[c], uwv);
                    rwv = fmaf(wr[c], xl[c], rwv);
                }

                const float yv = uwv * spline + sil * rwv;
                if (jo == 0) y0 += yv; else y1 += yv;
            }
        }
    }

    out[o0 * NPIX + pix] = y0;
    if (nO > 1)
        out[(o0 + 1) * NPIX + pix] = y1;
}

extern "C" void kernel_launch(void* const* d_in, const int* in_sizes, int n_in,
                              void* d_out, int out_size, void* d_ws, size_t ws_size,
                              hipStream_t stream) {
    const float* x  = (const float*)d_in[0];
    const float* gw = (const float*)d_in[1];
    const float* gb = (const float*)d_in[2];
    float* out = (float*)d_out;

    dim3 grid(NPIX / 64, 4);   // 256 pixel-groups x 4 o-groups = 1024 blocks
    dim3 block(256);           // 4 waves x 64 lanes
    hipLaunchKernelGGL(kan_fused3_kernel, grid, block, 0, stream, x, gw, gb, out);
}

// Round 4
// 49.795 us; speedup vs baseline: 9.0437x; 9.0437x over previous
//
#include <hip/hip_runtime.h>
#include <hip/hip_bf16.h>
#include <math.h>

#define IN_C 31
#define OUT_C 31
#define NUM_BASIS 8
#define NPIX 16384
#define UW_OFF 7688
#define RW_OFF 8649

typedef __attribute__((ext_vector_type(8))) short bf16x8;
typedef __attribute__((ext_vector_type(4))) float f32x4;

__device__ inline short f2bf(float f) {
    union { __hip_bfloat16 h; short s; } cv;
    cv.h = __float2bfloat16(f);   // RNE
    return cv.s;
}

// ---------------- prep: pack generator weights into MFMA B-fragment chunks ----
// ws layout: for i in [0,31): 20 chunks of 1 KB (20 KB per i, 620 KB total):
//   chunks 0..15 : spline B, chunk = kc*2 + nt  (kc in [0,8), nt in {0,1})
//   chunks 16,17 : uw B (nt 0,1);  chunks 18,19 : rw B (nt 0,1)
// chunk: lane l holds 8 bf16 at byte off l*16; elem j: B[k_local][col] with
//   k_local = c = (l>>4)*8 + j, col -> o = nt*16 + (l&15).
//   c==31 slot carries the bias (x~[31] = 1); o==31 is zero padding.
__global__ __launch_bounds__(64) void kan_prep_kernel(
    const float* __restrict__ gw, const float* __restrict__ gb,
    unsigned short* __restrict__ ws)
{
    const int blk = blockIdx.x;          // 31*20 = 620
    const int i   = blk / 20;
    const int ch  = blk % 20;
    const int l   = threadIdx.x;
    const int col = l & 15;
    const int krow = l >> 4;
    const int o = (ch & 1) * 16 + col;

    int p;
    if (ch < 16)      p = (i * 31 + o) * 8 + (ch >> 1);
    else if (ch < 18) p = UW_OFF + i * 31 + o;
    else              p = RW_OFF + i * 31 + o;

    bf16x8 v8;
#pragma unroll
    for (int j = 0; j < 8; ++j) {
        const int c = krow * 8 + j;
        float v = 0.f;
        if (o < OUT_C) v = (c < IN_C) ? gw[p * 31 + c] : gb[p];
        v8[j] = f2bf(v);
    }
    ((bf16x8*)ws)[blk * 64 + l] = v8;
}

// ---------------- main: fused generator-GEMM + KAN via MFMA --------------------
// Block = 512 thr = 8 waves, owns 32 pixels (2 M-tiles of 16). Wave w handles
// i in {w, w+8, ...}. Per i: spline GEMM K=256 (F = basis (x) x~ built
// in-register), uw GEMM K=32, rw GEMM K=32 with A = silu*x~ accumulated
// directly into Y. Then Y += UW*SP elementwise (same C layout). Cross-wave
// reduction of Y over i-sets via LDS atomicAdd.
__global__ __launch_bounds__(512, 2) void kan_mfma_kernel(
    const float* __restrict__ x,               // (31, 16384)
    const unsigned short* __restrict__ ws,     // packed B fragments
    float* __restrict__ out)                   // (31, 16384)
{
    const int t = threadIdx.x;
    const int l = t & 63;
    const int w = t >> 6;                      // 0..7
    const int pix0 = blockIdx.x * 32;

    __shared__ float xt[32 * 36];              // x~ tile, stride 36 (bank spread)
    __shared__ float yl[32 * 36];              // y accumulator

    // stage x~ (c==31 -> 1.0), zero yl
    for (int idx = t; idx < 32 * 32; idx += 512) {
        const int n = idx & 31, c = idx >> 5;
        xt[n * 36 + c] = (c < IN_C) ? x[c * NPIX + pix0 + n] : 1.0f;
    }
    for (int idx = t; idx < 32 * 36; idx += 512) yl[idx] = 0.f;
    __syncthreads();

    // per-lane x~ f32 (8 c-slots) + bf16 A-fragment, both M-tiles
    float xf[2][8];
    bf16x8 ax[2];
#pragma unroll
    for (int mt = 0; mt < 2; ++mt) {
        const int n = mt * 16 + (l & 15);
        const int cb = (l >> 4) * 8;
#pragma unroll
        for (int j = 0; j < 8; ++j) xf[mt][j] = xt[n * 36 + cb + j];
#pragma unroll
        for (int j = 0; j < 8; ++j) ax[mt][j] = f2bf(xf[mt][j]);
    }

    f32x4 Y[2][2];
#pragma unroll
    for (int mt = 0; mt < 2; ++mt)
#pragma unroll
        for (int nt = 0; nt < 2; ++nt) Y[mt][nt] = (f32x4){0.f, 0.f, 0.f, 0.f};

#pragma unroll 1
    for (int i = w; i < IN_C; i += 8) {
        // ---- per M-tile: basis (uniform cardinal cubic) + silu*x~ fragment ----
        float bas[2][8];
        bf16x8 arw[2];
#pragma unroll
        for (int mt = 0; mt < 2; ++mt) {
            const float xv = xt[(mt * 16 + (l & 15)) * 36 + i];
            const float tt = (xv + 2.2f) * 2.5f;
            const float jf = floorf(tt);
            const float u  = tt - jf;
            const int  jj  = (int)jf;
            const float u2 = u * u, u3 = u2 * u;
            const float n0 = u3 * (1.f / 6.f);                              // d=0
            const float n1 = (-3.f * u3 + 3.f * u2 + 3.f * u + 1.f) * (1.f / 6.f); // d=1
            const float n2 = (3.f * u3 - 6.f * u2 + 4.f) * (1.f / 6.f);     // d=2
            const float omu = 1.f - u;
            const float n3 = omu * omu * omu * (1.f / 6.f);                 // d=3
#pragma unroll
            for (int m = 0; m < 8; ++m) {
                const int d = jj - m;
                bas[mt][m] = (d == 0) ? n0 : (d == 1) ? n1 : (d == 2) ? n2
                           : (d == 3) ? n3 : 0.f;
            }
            const float sil = xv / (1.f + __expf(-xv));
#pragma unroll
            for (int j = 0; j < 8; ++j) arw[mt][j] = f2bf(sil * xf[mt][j]);
        }

        const bf16x8* bw = (const bf16x8*)ws + (size_t)i * 20 * 64;

        f32x4 SP[2][2], UW[2][2];
#pragma unroll
        for (int mt = 0; mt < 2; ++mt)
#pragma unroll
            for (int nt = 0; nt < 2; ++nt) {
                SP[mt][nt] = (f32x4){0.f, 0.f, 0.f, 0.f};
                UW[mt][nt] = (f32x4){0.f, 0.f, 0.f, 0.f};
            }

        // ---- spline GEMM: K = 256 = 8 kc-chunks; A-frag = bas[kc] * x~ ----
#pragma unroll
        for (int kc = 0; kc < 8; ++kc) {
            const bf16x8 b0 = bw[(kc * 2 + 0) * 64 + l];
            const bf16x8 b1 = bw[(kc * 2 + 1) * 64 + l];
#pragma unroll
            for (int mt = 0; mt < 2; ++mt) {
                bf16x8 af;
#pragma unroll
                for (int j = 0; j < 8; ++j) af[j] = f2bf(bas[mt][kc] * xf[mt][j]);
                SP[mt][0] = __builtin_amdgcn_mfma_f32_16x16x32_bf16(af, b0, SP[mt][0], 0, 0, 0);
                SP[mt][1] = __builtin_amdgcn_mfma_f32_16x16x32_bf16(af, b1, SP[mt][1], 0, 0, 0);
            }
        }
        // ---- uw GEMM (K=32) ----
        {
            const bf16x8 u0 = bw[16 * 64 + l];
            const bf16x8 u1 = bw[17 * 64 + l];
#pragma unroll
            for (int mt = 0; mt < 2; ++mt) {
                UW[mt][0] = __builtin_amdgcn_mfma_f32_16x16x32_bf16(ax[mt], u0, UW[mt][0], 0, 0, 0);
                UW[mt][1] = __builtin_amdgcn_mfma_f32_16x16x32_bf16(ax[mt], u1, UW[mt][1], 0, 0, 0);
            }
        }
        // ---- rw GEMM (K=32), A = silu*x~, accumulate straight into Y ----
        {
            const bf16x8 r0 = bw[18 * 64 + l];
            const bf16x8 r1 = bw[19 * 64 + l];
#pragma unroll
            for (int mt = 0; mt < 2; ++mt) {
                Y[mt][0] = __builtin_amdgcn_mfma_f32_16x16x32_bf16(arw[mt], r0, Y[mt][0], 0, 0, 0);
                Y[mt][1] = __builtin_amdgcn_mfma_f32_16x16x32_bf16(arw[mt], r1, Y[mt][1], 0, 0, 0);
            }
        }
        // ---- Y += UW * SP (elementwise, identical fragment layout) ----
#pragma unroll
        for (int mt = 0; mt < 2; ++mt)
#pragma unroll
            for (int nt = 0; nt < 2; ++nt)
#pragma unroll
                for (int r = 0; r < 4; ++r)
                    Y[mt][nt][r] += UW[mt][nt][r] * SP[mt][nt][r];
    }

    // ---- cross-wave reduction: C layout col = l&15 (o), row = (l>>4)*4+r (pixel)
#pragma unroll
    for (int mt = 0; mt < 2; ++mt)
#pragma unroll
        for (int nt = 0; nt < 2; ++nt)
#pragma unroll
            for (int r = 0; r < 4; ++r) {
                const int p = mt * 16 + (l >> 4) * 4 + r;
                const int o = nt * 16 + (l & 15);
                atomicAdd(&yl[p * 36 + o], Y[mt][nt][r]);
            }
    __syncthreads();

    for (int idx = t; idx < 32 * 32; idx += 512) {
        const int n = idx & 31, o = idx >> 5;
        if (o < OUT_C) out[o * NPIX + pix0 + n] = yl[n * 36 + o];
    }
}

extern "C" void kernel_launch(void* const* d_in, const int* in_sizes, int n_in,
                              void* d_out, int out_size, void* d_ws, size_t ws_size,
                              hipStream_t stream) {
    const float* x  = (const float*)d_in[0];
    const float* gw = (const float*)d_in[1];
    const float* gb = (const float*)d_in[2];
    float* out = (float*)d_out;
    unsigned short* ws = (unsigned short*)d_ws;

    hipLaunchKernelGGL(kan_prep_kernel, dim3(620), dim3(64), 0, stream, gw, gb, ws);
    hipLaunchKernelGGL(kan_mfma_kernel, dim3(NPIX / 32), dim3(512), 0, stream, x, ws, out);
}